// Round 14
// baseline (250.136 us; speedup 1.0000x reference)
//
#include <hip/hip_runtime.h>
#include <math.h>
#include <type_traits>

#define NN 65536      // nodes
#define NE 524288     // edges (without self loops)
#define NT (NN + NE)  // edges incl. self loops
#define NG 256        // groups
#define BN_EPS 1e-5f
#define NSLOT 64      // BN-stat partial slots

typedef __attribute__((ext_vector_type(8))) __bf16 bf16x8;
typedef __attribute__((ext_vector_type(4))) float f32x4;
typedef __attribute__((ext_vector_type(2))) float f32x2;

__device__ inline unsigned pk2(float lo, float hi) {
    unsigned a = (unsigned)__builtin_bit_cast(unsigned short, (__bf16)lo);
    unsigned b = (unsigned)__builtin_bit_cast(unsigned short, (__bf16)hi);
    return a | (b << 16);
}
__device__ inline void bf2(unsigned u, float& a, float& b) {
    a = __uint_as_float(u << 16);
    b = __uint_as_float(u & 0xFFFF0000u);
}
__device__ inline void unpk(uint4 u, float* v) {
    bf2(u.x, v[0], v[1]); bf2(u.y, v[2], v[3]);
    bf2(u.z, v[4], v[5]); bf2(u.w, v[6], v[7]);
}
__device__ inline void unpk(uint2 u, float* v) {
    bf2(u.x, v[0], v[1]); bf2(u.y, v[2], v[3]);
}
__device__ inline void unpk(unsigned u, float* v) { bf2(u, v[0], v[1]); }

// packed fp32 VALU (VOP3P, gfx90a+): compiler won't form these from scalar
__device__ inline f32x2 pk_fma(f32x2 a, f32x2 b, f32x2 c) {
    f32x2 d;
    asm("v_pk_fma_f32 %0, %1, %2, %3" : "=v"(d) : "v"(a), "v"(b), "v"(c));
    return d;
}
__device__ inline f32x2 pk_add(f32x2 a, f32x2 b) {
    f32x2 d;
    asm("v_pk_add_f32 %0, %1, %2" : "=v"(d) : "v"(a), "v"(b));
    return d;
}
__device__ inline f32x2 bf2v(unsigned u) {
    f32x2 r;
    r.x = __uint_as_float(u << 16);
    r.y = __uint_as_float(u & 0xFFFF0000u);
    return r;
}
__device__ inline void unpk2(uint4 u, f32x2* v) {
    v[0] = bf2v(u.x); v[1] = bf2v(u.y); v[2] = bf2v(u.z); v[3] = bf2v(u.w);
}
__device__ inline void unpk2(uint2 u, f32x2* v) {
    v[0] = bf2v(u.x); v[1] = bf2v(u.y);
}
__device__ inline void unpk2(unsigned u, f32x2* v) { v[0] = bf2v(u); }
__device__ inline f32x2 fabs2(f32x2 a) {
    f32x2 r;
    r.x = fabsf(a.x);
    r.y = fabsf(a.y);
    return r;
}

// ---------------- fat kernel: edge histogram  ||  W pre-swizzle ------------

__global__ __launch_bounds__(256) void k_pre(
        const int* __restrict__ ei, int* __restrict__ counts,
        const float* __restrict__ W1l, const float* __restrict__ W1r,
        const float* __restrict__ W2l, const float* __restrict__ W2r,
        const float* __restrict__ W3l, const float* __restrict__ W3r,
        unsigned short* __restrict__ f1l, unsigned short* __restrict__ f1r,
        unsigned short* __restrict__ f2l, unsigned short* __restrict__ f2r,
        unsigned short* __restrict__ f3l, unsigned short* __restrict__ f3r) {
    if (blockIdx.x < 2048) {
        int i = blockIdx.x * 256 + threadIdx.x;          // exactly covers NE
        atomicAdd(&counts[ei[NE + i]], 1);
        return;
    }
    int idx = (blockIdx.x - 2048) * 256 + threadIdx.x;   // [0, 6656)
    const float* W; unsigned short* Wf; int DO, base;
    if (idx < 2048)      { W = W1l; Wf = f1l; DO = 128; base = 0; }
    else if (idx < 4096) { W = W1r; Wf = f1r; DO = 128; base = 2048; }
    else if (idx < 5120) { W = W2l; Wf = f2l; DO = 64;  base = 4096; }
    else if (idx < 6144) { W = W2r; Wf = f2r; DO = 64;  base = 5120; }
    else if (idx < 6400) { W = W3l; Wf = f3l; DO = 32;  base = 6144; }
    else                 { W = W3r; Wf = f3r; DO = 32;  base = 6400; }
    int li = idx - base;
    int lane = li & 63;
    int fr = li >> 6;
    int nf = fr % (DO / 16);
    int kk = fr / (DO / 16);
    int k0 = kk * 32 + (lane >> 4) * 8;
    int c = nf * 16 + (lane & 15);
    unsigned short o[8];
#pragma unroll
    for (int j = 0; j < 8; ++j)
        o[j] = __builtin_bit_cast(unsigned short, (__bf16)W[(size_t)(k0 + j) * DO + c]);
    uint4 p;
    p.x = o[0] | ((unsigned)o[1] << 16);
    p.y = o[2] | ((unsigned)o[3] << 16);
    p.z = o[4] | ((unsigned)o[5] << 16);
    p.w = o[6] | ((unsigned)o[7] << 16);
    ((uint4*)(Wf))[li] = p;
}

// ---------------- scan stage A: per-256-chunk sums --------------------------

__global__ void k_scanA(const int* __restrict__ counts, int* __restrict__ bsum) {
    __shared__ int l[256];
    int t = threadIdx.x;
    int v = counts[blockIdx.x * 256 + t] + 1;   // +1 self loop
    l[t] = v;
    __syncthreads();
    for (int st = 128; st > 0; st >>= 1) {
        if (t < st) l[t] += l[t + st];
        __syncthreads();
    }
    if (t == 0) bsum[blockIdx.x] = l[0];
}

// ---------------- scan stage BC: each block re-scans bsum in LDS ------------

__global__ void k_scanBC(const int* __restrict__ counts, const int* __restrict__ bsum,
                         int* __restrict__ off, int* __restrict__ wofs) {
    __shared__ int lb[256];
    __shared__ int l[256];
    int t = threadIdx.x;
    int bv = bsum[t];
    lb[t] = bv;
    __syncthreads();
    for (int d = 1; d < 256; d <<= 1) {
        int u = (t >= d) ? lb[t - d] : 0;
        __syncthreads();
        lb[t] += u;
        __syncthreads();
    }
    int boffv = lb[blockIdx.x] - bsum[blockIdx.x];  // exclusive prefix for block
    int i = blockIdx.x * 256 + t;
    int v = counts[i] + 1;                          // +1 self loop
    l[t] = v;
    __syncthreads();
    for (int d = 1; d < 256; d <<= 1) {
        int u = (t >= d) ? l[t - d] : 0;
        __syncthreads();
        l[t] += u;
        __syncthreads();
    }
    int e = boffv + l[t] - v;
    off[i] = e;
    wofs[i] = e;
    if (i == 0) off[NN] = NT;
}

// ---------------- CSR scatter: 4 edges/thread, two-phase for atomic ILP -----

__global__ __launch_bounds__(256) void k_scatter(
        const int* __restrict__ ei, const int* __restrict__ batch,
        int* __restrict__ wofs, int* __restrict__ csr_src,
        int* __restrict__ gstart, int* __restrict__ gend) {
    int base = blockIdx.x * 1024 + threadIdx.x;   // 576 blocks cover NT exactly
    int srcv[4], posv[4];
#pragma unroll
    for (int k = 0; k < 4; ++k) {
        int i = base + k * 256;
        if (i < NN) {
            int b = batch[i];
            if (i == 0) gstart[b] = 0;
            if (i == NN - 1) gend[b] = NN;
            else {
                int b2 = batch[i + 1];
                if (b2 != b) { gend[b] = i + 1; gstart[b2] = i + 1; }
            }
        }
        int src, dst;
        if (i < NE) { src = ei[i]; dst = ei[NE + i]; }
        else        { src = dst = i - NE; }
        srcv[k] = src;
        posv[k] = atomicAdd(&wofs[dst], 1);       // 4 independent in flight
    }
#pragma unroll
    for (int k = 0; k < 4; ++k) csr_src[posv[k]] = srcv[k];
}

// ------- fused dual GEMM via bf16 MFMA: xl = x@Wl+bl, xr = x@Wr+br ---------
// XT=float: fp32 input (layer 1). XT=ushort: bf16 input (layers 2,3; the
// deferred-BN affine is applied after unpacking). Deferred-BN scale/shift is
// reduced from NSLOT fp32 partial slots in the prologue.

template <int DI, int DO, bool BN, typename XT>
__global__ __launch_bounds__(256) void k_gemm2m(
        const XT* __restrict__ x,
        const unsigned short* __restrict__ Wfl, const unsigned short* __restrict__ Wfr,
        const float* __restrict__ bl, const float* __restrict__ br,
        const float* __restrict__ stats, const float* __restrict__ bg,
        const float* __restrict__ bb,
        unsigned short* __restrict__ xl, unsigned short* __restrict__ xr) {
    constexpr int NF = DO / 16;
    constexpr int NK = DI / 32;
    const int lane = threadIdx.x & 63;
    const int wid = threadIdx.x >> 6;
    const int lg = lane >> 4, ll = lane & 15;
    const int nbase = blockIdx.x * 128 + wid * 32;

    __shared__ float sbn[BN ? 2 * DI : 2];
    float* ssc = sbn;
    float* ssh = sbn + (BN ? DI : 1);
    if constexpr (BN) {
        int t = threadIdx.x;
        if (t < DI) {
            float s = 0.f, q = 0.f;
            for (int k = 0; k < NSLOT; ++k) {
                s += stats[k * 2 * DI + t];
                q += stats[k * 2 * DI + DI + t];
            }
            float mean = s * (1.f / NN);
            float var = q * (1.f / NN) - mean * mean;
            float sc = bg[t] * rsqrtf(var + BN_EPS);
            ssc[t] = sc;
            ssh[t] = bb[t] - mean * sc;
        }
        __syncthreads();
    }

    f32x4 acc[2][NF][2] = {};

    for (int kk = 0; kk < NK; ++kk) {
        const int k0 = kk * 32 + lg * 8;
        float4 sca, scb, sha, shb;
        if constexpr (BN) {
            sca = *(const float4*)(ssc + k0);
            scb = *(const float4*)(ssc + k0 + 4);
            sha = *(const float4*)(ssh + k0);
            shb = *(const float4*)(ssh + k0 + 4);
        }
        bf16x8 xa[2];
#pragma unroll
        for (int nm = 0; nm < 2; ++nm) {
            float w[8];
            if constexpr (std::is_same<XT, float>::value) {
                const float* xp = x + (size_t)(nbase + nm * 16 + ll) * DI + k0;
                float4 v0 = *(const float4*)xp;
                float4 v1 = *(const float4*)(xp + 4);
                w[0] = v0.x; w[1] = v0.y; w[2] = v0.z; w[3] = v0.w;
                w[4] = v1.x; w[5] = v1.y; w[6] = v1.z; w[7] = v1.w;
            } else {
                const unsigned short* xp = x + (size_t)(nbase + nm * 16 + ll) * DI + k0;
                unpk(*(const uint4*)xp, w);
            }
            if constexpr (BN) {
                w[0] = w[0] * sca.x + sha.x;
                w[1] = w[1] * sca.y + sha.y;
                w[2] = w[2] * sca.z + sha.z;
                w[3] = w[3] * sca.w + sha.w;
                w[4] = w[4] * scb.x + shb.x;
                w[5] = w[5] * scb.y + shb.y;
                w[6] = w[6] * scb.z + shb.z;
                w[7] = w[7] * scb.w + shb.w;
            }
            bf16x8 t;
#pragma unroll
            for (int j = 0; j < 8; ++j) t[j] = (__bf16)w[j];
            xa[nm] = t;
        }
        const unsigned short* wlp = Wfl + ((size_t)(kk * NF) * 64 + lane) * 8;
        const unsigned short* wrp = Wfr + ((size_t)(kk * NF) * 64 + lane) * 8;
#pragma unroll
        for (int nf = 0; nf < NF; ++nf) {
            bf16x8 wl = __builtin_bit_cast(bf16x8, *(const uint4*)(wlp + (size_t)nf * 64 * 8));
            bf16x8 wr = __builtin_bit_cast(bf16x8, *(const uint4*)(wrp + (size_t)nf * 64 * 8));
#pragma unroll
            for (int nm = 0; nm < 2; ++nm) {
                acc[nm][nf][0] = __builtin_amdgcn_mfma_f32_16x16x32_bf16(wl, xa[nm], acc[nm][nf][0], 0, 0, 0);
                acc[nm][nf][1] = __builtin_amdgcn_mfma_f32_16x16x32_bf16(wr, xa[nm], acc[nm][nf][1], 0, 0, 0);
            }
        }
    }

    // epilogue: +bias, pack 4 consecutive channels to bf16, store uint2
#pragma unroll
    for (int nf = 0; nf < NF; ++nf) {
        float4 blv = *(const float4*)(bl + nf * 16 + lg * 4);
        float4 brv = *(const float4*)(br + nf * 16 + lg * 4);
#pragma unroll
        for (int nm = 0; nm < 2; ++nm) {
            size_t base = (size_t)(nbase + nm * 16 + ll) * DO + nf * 16 + lg * 4;
            f32x4 a = acc[nm][nf][0];
            uint2 p;
            p.x = pk2(a[0] + blv.x, a[1] + blv.y);
            p.y = pk2(a[2] + blv.z, a[3] + blv.w);
            *(uint2*)(xl + base) = p;
            f32x4 r = acc[nm][nf][1];
            uint2 q;
            q.x = pk2(r[0] + brv.x, r[1] + brv.y);
            q.y = pk2(r[2] + brv.z, r[3] + brv.w);
            *(uint2*)(xr + base) = q;
        }
    }
}

// ------- per-node softmax attention + aggregate + bias + relu --------------
// R13 agg10 structure (256-thread block = 16 nodes, 4 nodes/wave, 4 edges in
// flight, prefetch; LDS-combined stats+pool flush) with the inner loop
// rewritten on packed fp32 VALU (v_pk_add/v_pk_fma). leaky_0.2(t) is computed
// exactly as 0.6t + 0.4|t| with 0.6*att / 0.4*att folded into constants.

template <int DO, bool WRITEH, int PBASE>
__global__ __launch_bounds__(256) void k_agg11(
        const unsigned short* __restrict__ xl, const unsigned short* __restrict__ xr,
        const int* __restrict__ off, const int* __restrict__ srcs,
        const float* __restrict__ att, const float* __restrict__ bias,
        const int* __restrict__ batch,
        unsigned short* __restrict__ hout, float* __restrict__ statbuf,
        float* __restrict__ rawpool) {
    constexpr int CPL = DO / 16;   // channels per lane
    constexpr int CP2 = CPL / 2;   // float2 pairs per lane
    using UT = typename std::conditional<CPL == 8, uint4,
               typename std::conditional<CPL == 4, uint2, unsigned>::type>::type;
    int wid = threadIdx.x >> 6;
    int lane = threadIdx.x & 63;
    int sg = lane >> 4;          // subgroup 0..3
    int sl = lane & 15;
    int cbase = sl * CPL;

    __shared__ float sO[16][DO];
    __shared__ int gb[16];
    if (threadIdx.x < 16) gb[threadIdx.x] = batch[blockIdx.x * 16 + threadIdx.x];

    f32x2 at6[CP2], at4[CP2];
#pragma unroll
    for (int i = 0; i < CP2; ++i) {
        float a0 = att[cbase + 2 * i], a1 = att[cbase + 2 * i + 1];
        at6[i].x = 0.6f * a0; at6[i].y = 0.6f * a1;
        at4[i].x = 0.4f * a0; at4[i].y = 0.4f * a1;
    }
    float bi[CPL];
#pragma unroll
    for (int i = 0; i < CPL; ++i) bi[i] = bias[cbase + i];

    int nb = blockIdx.x * 16 + wid * 4;
    for (int n = 0; n < 4; ++n) {
        int node = nb + n;
        f32x2 xr2[CP2];
        unpk2(*(const UT*)(xr + (size_t)node * DO + cbase), xr2);
        float spart = 0.f;
        f32x2 acc2[CP2] = {};
        int e0 = off[node], e1 = off[node + 1];

        int jp = e0 + sg;                 // prefetch iteration 0
        bool actp = (jp < e1);
        int srcp = srcs[actp ? jp : e1 - 1];
        UT up = *(const UT*)(xl + (size_t)srcp * DO + cbase);

        for (int jb = e0; jb < e1; jb += 4) {
            UT u = up;
            bool act = actp;
            if (jb + 4 < e1) {            // prefetch next iteration
                int jn = jb + 4 + sg;
                actp = (jn < e1);
                int srcn = srcs[actp ? jn : e1 - 1];
                up = *(const UT*)(xl + (size_t)srcn * DO + cbase);
            }
            f32x2 v2[CP2];
            unpk2(u, v2);
            f32x2 pd2 = {0.f, 0.f};
#pragma unroll
            for (int i = 0; i < CP2; ++i) {
                f32x2 t2 = pk_add(v2[i], xr2[i]);   // t = v + xr
                pd2 = pk_fma(t2, at6[i], pd2);      // += 0.6*att * t
                pd2 = pk_fma(fabs2(t2), at4[i], pd2);  // += 0.4*att * |t|
            }
            float pd = pd2.x + pd2.y;
#pragma unroll
            for (int d = 1; d < 16; d <<= 1) pd += __shfl_xor(pd, d);
            float w = act ? __expf(pd) : 0.f;
            spart += w;
            f32x2 w2 = {w, w};
#pragma unroll
            for (int i = 0; i < CP2; ++i) acc2[i] = pk_fma(w2, v2[i], acc2[i]);
        }
        spart += __shfl_xor(spart, 16);
        spart += __shfl_xor(spart, 32);
#pragma unroll
        for (int i = 0; i < CP2; ++i) {
            f32x2 o1, o2;
            o1.x = __shfl_xor(acc2[i].x, 16);
            o1.y = __shfl_xor(acc2[i].y, 16);
            acc2[i] = pk_add(acc2[i], o1);
            o2.x = __shfl_xor(acc2[i].x, 32);
            o2.y = __shfl_xor(acc2[i].y, 32);
            acc2[i] = pk_add(acc2[i], o2);
        }
        if (sg == 0) {
            float inv = 1.f / spart;
            float o[CPL];
#pragma unroll
            for (int i = 0; i < CPL; ++i) {
                float a = (i & 1) ? acc2[i >> 1].y : acc2[i >> 1].x;
                o[i] = fmaxf(fmaf(a, inv, bi[i]), 0.f);
                sO[wid * 4 + n][cbase + i] = o[i];
            }
            if constexpr (WRITEH) {
                if constexpr (CPL == 8) {
                    uint4 pkd;
                    pkd.x = pk2(o[0], o[1]); pkd.y = pk2(o[2], o[3]);
                    pkd.z = pk2(o[4], o[5]); pkd.w = pk2(o[6], o[7]);
                    *(uint4*)(hout + (size_t)node * DO + cbase) = pkd;
                } else if constexpr (CPL == 4) {
                    uint2 pkd;
                    pkd.x = pk2(o[0], o[1]); pkd.y = pk2(o[2], o[3]);
                    *(uint2*)(hout + (size_t)node * DO + cbase) = pkd;
                } else {
                    *(unsigned*)(hout + (size_t)node * DO + cbase) = pk2(o[0], o[1]);
                }
            }
        }
    }
    __syncthreads();
    int t = threadIdx.x;
    if (t < DO) {
        float pa = sO[0][t];
        float s = pa, q = pa * pa;
        int cg = gb[0];
#pragma unroll
        for (int w = 1; w < 16; ++w) {
            float vw = sO[w][t];
            s += vw;
            q += vw * vw;
            int g = gb[w];
            if (g != cg) {               // group boundary (sorted batch)
                atomicAdd(&rawpool[(size_t)cg * 224 + PBASE + t], pa);
                pa = 0.f;
                cg = g;
            }
            pa += vw;
        }
        atomicAdd(&rawpool[(size_t)cg * 224 + PBASE + t], pa);
        float* sb = statbuf + (size_t)(blockIdx.x & (NSLOT - 1)) * 2 * DO;
        atomicAdd(&sb[t], s);
        atomicAdd(&sb[DO + t], q);
    }
}

// ---------------- head: build pooled row (BN affines from fused stats), ----
// ---------------- lin1+relu; then BN5+lin2+sigmoid/log_softmax -------------

__global__ __launch_bounds__(128) void k_head1(
        const float* __restrict__ rawpool,
        const int* __restrict__ gstart, const int* __restrict__ gend,
        const float* __restrict__ st1, const float* __restrict__ st2,
        const float* __restrict__ st3,
        const float* __restrict__ g1, const float* __restrict__ b1,
        const float* __restrict__ g2, const float* __restrict__ b2,
        const float* __restrict__ g3, const float* __restrict__ b3,
        const float* __restrict__ W1, const float* __restrict__ b1l,
        float* __restrict__ z) {
    __shared__ float row[256];
    int g = blockIdx.x, c = threadIdx.x;  // 128 threads
    float cnt = (float)(gend[g] - gstart[g]);
    {
        float s = 0.f, q = 0.f;
        for (int k = 0; k < NSLOT; ++k) {
            s += st1[k * 256 + c];
            q += st1[k * 256 + 128 + c];
        }
        float mean = s * (1.f / NN);
        float var = q * (1.f / NN) - mean * mean;
        float sc = g1[c] * rsqrtf(var + BN_EPS);
        float sh = b1[c] - mean * sc;
        row[c] = sc * rawpool[(size_t)g * 224 + c] + sh * cnt;
    }
    {
        float sc, sh, rv;
        if (c < 64) {
            float s = 0.f, q = 0.f;
            for (int k = 0; k < NSLOT; ++k) {
                s += st2[k * 128 + c];
                q += st2[k * 128 + 64 + c];
            }
            float mean = s * (1.f / NN);
            float var = q * (1.f / NN) - mean * mean;
            sc = g2[c] * rsqrtf(var + BN_EPS);
            sh = b2[c] - mean * sc;
            rv = rawpool[(size_t)g * 224 + 128 + c];
        } else {
            int j = (c < 96) ? c - 64 : c - 96;
            float s = 0.f, q = 0.f;
            for (int k = 0; k < NSLOT; ++k) {
                s += st3[k * 64 + j];
                q += st3[k * 64 + 32 + j];
            }
            float mean = s * (1.f / NN);
            float var = q * (1.f / NN) - mean * mean;
            sc = g3[j] * rsqrtf(var + BN_EPS);
            sh = b3[j] - mean * sc;
            rv = rawpool[(size_t)g * 224 + 192 + j];
        }
        row[128 + c] = sc * rv + sh * cnt;
    }
    __syncthreads();
    float acc = b1l[c];
#pragma unroll 16
    for (int k = 0; k < 256; ++k) acc += row[k] * W1[k * 128 + c];
    z[g * 128 + c] = acc > 0.f ? acc : 0.f;
}

__global__ void k_head2(const float* __restrict__ z, const float* __restrict__ g5,
                        const float* __restrict__ b5, const float* __restrict__ W2,
                        const float* __restrict__ b2, float* __restrict__ out) {
    __shared__ float row[128];
    __shared__ float lg[3];
    int g = blockIdx.x, t = threadIdx.x;
    double s = 0.0, q = 0.0;
    for (int gg = 0; gg < NG; ++gg) {
        float v = z[gg * 128 + t];
        s += v;
        q += (double)v * v;
    }
    double mean = s * (1.0 / NG);
    double var = q * (1.0 / NG) - mean * mean;
    float sc = g5[t] * rsqrtf((float)var + BN_EPS);
    float sh = b5[t] - (float)mean * sc;
    row[t] = z[g * 128 + t] * sc + sh;
    __syncthreads();
    if (t < 3) {
        float acc = b2[t];
        for (int k = 0; k < 128; ++k) acc += row[k] * W2[k * 3 + t];
        lg[t] = acc;
    }
    __syncthreads();
    if (t == 0) {
        float l0 = lg[0], l1 = lg[1], l2 = lg[2];
        float mx = fmaxf(l0, fmaxf(l1, l2));
        float lse = mx + logf(expf(l0 - mx) + expf(l1 - mx) + expf(l2 - mx));
        out[g * 3 + 0] = 1.f / (1.f + expf(-l0));
        out[g * 3 + 1] = 1.f / (1.f + expf(-l1));
        out[g * 3 + 2] = 1.f / (1.f + expf(-l2));
        out[NG * 3 + g * 3 + 0] = l0 - lse;
        out[NG * 3 + g * 3 + 1] = l1 - lse;
        out[NG * 3 + g * 3 + 2] = l2 - lse;
    }
}

// ---------------------------------------------------------------------------

extern "C" void kernel_launch(void* const* d_in, const int* in_sizes, int n_in,
                              void* d_out, int out_size, void* d_ws, size_t ws_size,
                              hipStream_t stream) {
    const float* x   = (const float*)d_in[0];
    const int* ei    = (const int*)d_in[1];
    const int* batch = (const int*)d_in[2];
    auto F = [&](int i) { return (const float*)d_in[i]; };

    char* ws = (char*)d_ws;
    size_t o = 0;
    auto alloc = [&](size_t bytes) {
        char* p = ws + o;
        o += (bytes + 255) & ~(size_t)255;
        return p;
    };
    int* csr_off  = (int*)alloc((NN + 1) * 4);
    int* wofs     = (int*)alloc(NN * 4);
    int* bsum     = (int*)alloc(256 * 4);
    int* csr_src  = (int*)alloc((size_t)NT * 4);
    unsigned short* xl = (unsigned short*)alloc((size_t)NN * 128 * 2);
    unsigned short* xr = (unsigned short*)alloc((size_t)NN * 128 * 2);
    unsigned short* h1 = (unsigned short*)alloc((size_t)NN * 128 * 2);
    unsigned short* h2 = (unsigned short*)alloc((size_t)NN * 64 * 2);
    float* z      = (float*)alloc(NG * 128 * 4);
    // zero-init chunk: counts|stat1|stat2|stat3|rawpool|gstart|gend (one memset)
    size_t zbytes = (size_t)NN * 4 + (size_t)NSLOT * (256 + 128 + 64) * 4 +
                    (size_t)NG * 224 * 4 + 2 * NG * 4;
    char* zchunk  = alloc(zbytes);
    int* counts   = (int*)zchunk;                         // [NN]
    float* stat1  = (float*)(zchunk + (size_t)NN * 4);    // [64][256]
    float* stat2  = stat1 + NSLOT * 256;                  // [64][128]
    float* stat3  = stat2 + NSLOT * 128;                  // [64][64]
    float* rawpool = stat3 + NSLOT * 64;                  // [256][224]
    int* gstart   = (int*)(rawpool + (size_t)NG * 224);   // [256]
    int* gend     = gstart + NG;                          // [256]
    unsigned short* wfl1 = (unsigned short*)alloc(128 * 128 * 2);
    unsigned short* wfr1 = (unsigned short*)alloc(128 * 128 * 2);
    unsigned short* wfl2 = (unsigned short*)alloc(128 * 64 * 2);
    unsigned short* wfr2 = (unsigned short*)alloc(128 * 64 * 2);
    unsigned short* wfl3 = (unsigned short*)alloc(64 * 32 * 2);
    unsigned short* wfr3 = (unsigned short*)alloc(64 * 32 * 2);

    hipMemsetAsync(zchunk, 0, zbytes, stream);

    // hist || W swizzle (independent work, one dispatch)
    k_pre<<<2048 + 26, 256, 0, stream>>>(ei, counts,
                                         F(3), F(5), F(11), F(13), F(19), F(21),
                                         wfl1, wfr1, wfl2, wfr2, wfl3, wfr3);
    k_scanA<<<NN / 256, 256, 0, stream>>>(counts, bsum);
    k_scanBC<<<NN / 256, 256, 0, stream>>>(counts, bsum, csr_off, wofs);
    k_scatter<<<NT / 1024, 256, 0, stream>>>(ei, batch, wofs, csr_src,
                                             gstart, gend);

    // ---- GAT layer 1: 128 -> 128 (stats + pool fused into agg) ----
    k_gemm2m<128, 128, false, float><<<NN / 128, 256, 0, stream>>>(
        x, wfl1, wfr1, F(4), F(6), nullptr, nullptr, nullptr, xl, xr);
    k_agg11<128, true, 0><<<NN / 16, 256, 0, stream>>>(
        xl, xr, csr_off, csr_src, F(7), F(8), batch, h1, stat1, rawpool);

    // ---- GAT layer 2: 128 -> 64 (bf16 h1; BN1 affine in prologue) ----
    k_gemm2m<128, 64, true, unsigned short><<<NN / 128, 256, 0, stream>>>(
        h1, wfl2, wfr2, F(12), F(14), stat1, F(9), F(10), xl, xr);
    k_agg11<64, true, 128><<<NN / 16, 256, 0, stream>>>(
        xl, xr, csr_off, csr_src, F(15), F(16), batch, h2, stat2, rawpool);

    // ---- GAT layer 3: 64 -> 32 (bf16 h2; h3 never materialized) ----
    k_gemm2m<64, 32, true, unsigned short><<<NN / 128, 256, 0, stream>>>(
        h2, wfl3, wfr3, F(20), F(22), stat2, F(17), F(18), xl, xr);
    k_agg11<32, false, 192><<<NN / 16, 256, 0, stream>>>(
        xl, xr, csr_off, csr_src, F(23), F(24), batch, nullptr, stat3, rawpool);

    // ---- head ----
    k_head1<<<NG, 128, 0, stream>>>(rawpool, gstart, gend, stat1, stat2, stat3,
                                    F(9), F(10), F(17), F(18), F(25), F(26),
                                    F(27), F(28), z);
    k_head2<<<NG, 128, 0, stream>>>(z, F(29), F(30), F(31), F(32), (float*)d_out);
}

// Round 15
// 236.461 us; speedup vs baseline: 1.0578x; 1.0578x over previous
//
#include <hip/hip_runtime.h>
#include <math.h>
#include <type_traits>

#define NN 65536      // nodes
#define NE 524288     // edges (without self loops)
#define NT (NN + NE)  // edges incl. self loops
#define NG 256        // groups
#define BN_EPS 1e-5f
#define NSLOT 64      // BN-stat partial slots

typedef __attribute__((ext_vector_type(8))) __bf16 bf16x8;
typedef __attribute__((ext_vector_type(4))) float f32x4;

__device__ inline unsigned pk2(float lo, float hi) {
    unsigned a = (unsigned)__builtin_bit_cast(unsigned short, (__bf16)lo);
    unsigned b = (unsigned)__builtin_bit_cast(unsigned short, (__bf16)hi);
    return a | (b << 16);
}
__device__ inline void bf2(unsigned u, float& a, float& b) {
    a = __uint_as_float(u << 16);
    b = __uint_as_float(u & 0xFFFF0000u);
}
__device__ inline void unpk(uint4 u, float* v) {
    bf2(u.x, v[0], v[1]); bf2(u.y, v[2], v[3]);
    bf2(u.z, v[4], v[5]); bf2(u.w, v[6], v[7]);
}
__device__ inline void unpk(uint2 u, float* v) {
    bf2(u.x, v[0], v[1]); bf2(u.y, v[2], v[3]);
}
__device__ inline void unpk(unsigned u, float* v) { bf2(u, v[0], v[1]); }

// ---------------- fat kernel: edge histogram  ||  W pre-swizzle ------------

__global__ __launch_bounds__(256) void k_pre(
        const int* __restrict__ ei, int* __restrict__ counts,
        const float* __restrict__ W1l, const float* __restrict__ W1r,
        const float* __restrict__ W2l, const float* __restrict__ W2r,
        const float* __restrict__ W3l, const float* __restrict__ W3r,
        unsigned short* __restrict__ f1l, unsigned short* __restrict__ f1r,
        unsigned short* __restrict__ f2l, unsigned short* __restrict__ f2r,
        unsigned short* __restrict__ f3l, unsigned short* __restrict__ f3r) {
    if (blockIdx.x < 2048) {
        int i = blockIdx.x * 256 + threadIdx.x;          // exactly covers NE
        atomicAdd(&counts[ei[NE + i]], 1);
        return;
    }
    int idx = (blockIdx.x - 2048) * 256 + threadIdx.x;   // [0, 6656)
    const float* W; unsigned short* Wf; int DO, base;
    if (idx < 2048)      { W = W1l; Wf = f1l; DO = 128; base = 0; }
    else if (idx < 4096) { W = W1r; Wf = f1r; DO = 128; base = 2048; }
    else if (idx < 5120) { W = W2l; Wf = f2l; DO = 64;  base = 4096; }
    else if (idx < 6144) { W = W2r; Wf = f2r; DO = 64;  base = 5120; }
    else if (idx < 6400) { W = W3l; Wf = f3l; DO = 32;  base = 6144; }
    else                 { W = W3r; Wf = f3r; DO = 32;  base = 6400; }
    int li = idx - base;
    int lane = li & 63;
    int fr = li >> 6;
    int nf = fr % (DO / 16);
    int kk = fr / (DO / 16);
    int k0 = kk * 32 + (lane >> 4) * 8;
    int c = nf * 16 + (lane & 15);
    unsigned short o[8];
#pragma unroll
    for (int j = 0; j < 8; ++j)
        o[j] = __builtin_bit_cast(unsigned short, (__bf16)W[(size_t)(k0 + j) * DO + c]);
    uint4 p;
    p.x = o[0] | ((unsigned)o[1] << 16);
    p.y = o[2] | ((unsigned)o[3] << 16);
    p.z = o[4] | ((unsigned)o[5] << 16);
    p.w = o[6] | ((unsigned)o[7] << 16);
    ((uint4*)(Wf))[li] = p;
}

// ---------------- scan stage A: per-256-chunk sums --------------------------

__global__ void k_scanA(const int* __restrict__ counts, int* __restrict__ bsum) {
    __shared__ int l[256];
    int t = threadIdx.x;
    int v = counts[blockIdx.x * 256 + t] + 1;   // +1 self loop
    l[t] = v;
    __syncthreads();
    for (int st = 128; st > 0; st >>= 1) {
        if (t < st) l[t] += l[t + st];
        __syncthreads();
    }
    if (t == 0) bsum[blockIdx.x] = l[0];
}

// ---------------- scan stage BC: each block re-scans bsum in LDS ------------

__global__ void k_scanBC(const int* __restrict__ counts, const int* __restrict__ bsum,
                         int* __restrict__ off, int* __restrict__ wofs) {
    __shared__ int lb[256];
    __shared__ int l[256];
    int t = threadIdx.x;
    int bv = bsum[t];
    lb[t] = bv;
    __syncthreads();
    for (int d = 1; d < 256; d <<= 1) {
        int u = (t >= d) ? lb[t - d] : 0;
        __syncthreads();
        lb[t] += u;
        __syncthreads();
    }
    int boffv = lb[blockIdx.x] - bsum[blockIdx.x];  // exclusive prefix for block
    int i = blockIdx.x * 256 + t;
    int v = counts[i] + 1;                          // +1 self loop
    l[t] = v;
    __syncthreads();
    for (int d = 1; d < 256; d <<= 1) {
        int u = (t >= d) ? l[t - d] : 0;
        __syncthreads();
        l[t] += u;
        __syncthreads();
    }
    int e = boffv + l[t] - v;
    off[i] = e;
    wofs[i] = e;
    if (i == 0) off[NN] = NT;
}

// ---------------- CSR scatter: 4 edges/thread, two-phase for atomic ILP -----

__global__ __launch_bounds__(256) void k_scatter(
        const int* __restrict__ ei, const int* __restrict__ batch,
        int* __restrict__ wofs, int* __restrict__ csr_src,
        int* __restrict__ gstart, int* __restrict__ gend) {
    int base = blockIdx.x * 1024 + threadIdx.x;   // 576 blocks cover NT exactly
    int srcv[4], posv[4];
#pragma unroll
    for (int k = 0; k < 4; ++k) {
        int i = base + k * 256;
        if (i < NN) {
            int b = batch[i];
            if (i == 0) gstart[b] = 0;
            if (i == NN - 1) gend[b] = NN;
            else {
                int b2 = batch[i + 1];
                if (b2 != b) { gend[b] = i + 1; gstart[b2] = i + 1; }
            }
        }
        int src, dst;
        if (i < NE) { src = ei[i]; dst = ei[NE + i]; }
        else        { src = dst = i - NE; }
        srcv[k] = src;
        posv[k] = atomicAdd(&wofs[dst], 1);       // 4 independent in flight
    }
#pragma unroll
    for (int k = 0; k < 4; ++k) csr_src[posv[k]] = srcv[k];
}

// ------- fused dual GEMM via bf16 MFMA: xl = x@Wl+bl, xr = x@Wr+br ---------
// XT=float: fp32 input (layer 1). XT=ushort: bf16 input (layers 2,3; the
// deferred-BN affine is applied after unpacking). Deferred-BN scale/shift is
// reduced from NSLOT fp32 partial slots in the prologue.

template <int DI, int DO, bool BN, typename XT>
__global__ __launch_bounds__(256) void k_gemm2m(
        const XT* __restrict__ x,
        const unsigned short* __restrict__ Wfl, const unsigned short* __restrict__ Wfr,
        const float* __restrict__ bl, const float* __restrict__ br,
        const float* __restrict__ stats, const float* __restrict__ bg,
        const float* __restrict__ bb,
        unsigned short* __restrict__ xl, unsigned short* __restrict__ xr) {
    constexpr int NF = DO / 16;
    constexpr int NK = DI / 32;
    const int lane = threadIdx.x & 63;
    const int wid = threadIdx.x >> 6;
    const int lg = lane >> 4, ll = lane & 15;
    const int nbase = blockIdx.x * 128 + wid * 32;

    __shared__ float sbn[BN ? 2 * DI : 2];
    float* ssc = sbn;
    float* ssh = sbn + (BN ? DI : 1);
    if constexpr (BN) {
        int t = threadIdx.x;
        if (t < DI) {
            float s = 0.f, q = 0.f;
            for (int k = 0; k < NSLOT; ++k) {
                s += stats[k * 2 * DI + t];
                q += stats[k * 2 * DI + DI + t];
            }
            float mean = s * (1.f / NN);
            float var = q * (1.f / NN) - mean * mean;
            float sc = bg[t] * rsqrtf(var + BN_EPS);
            ssc[t] = sc;
            ssh[t] = bb[t] - mean * sc;
        }
        __syncthreads();
    }

    f32x4 acc[2][NF][2] = {};

    for (int kk = 0; kk < NK; ++kk) {
        const int k0 = kk * 32 + lg * 8;
        float4 sca, scb, sha, shb;
        if constexpr (BN) {
            sca = *(const float4*)(ssc + k0);
            scb = *(const float4*)(ssc + k0 + 4);
            sha = *(const float4*)(ssh + k0);
            shb = *(const float4*)(ssh + k0 + 4);
        }
        bf16x8 xa[2];
#pragma unroll
        for (int nm = 0; nm < 2; ++nm) {
            float w[8];
            if constexpr (std::is_same<XT, float>::value) {
                const float* xp = x + (size_t)(nbase + nm * 16 + ll) * DI + k0;
                float4 v0 = *(const float4*)xp;
                float4 v1 = *(const float4*)(xp + 4);
                w[0] = v0.x; w[1] = v0.y; w[2] = v0.z; w[3] = v0.w;
                w[4] = v1.x; w[5] = v1.y; w[6] = v1.z; w[7] = v1.w;
            } else {
                const unsigned short* xp = x + (size_t)(nbase + nm * 16 + ll) * DI + k0;
                unpk(*(const uint4*)xp, w);
            }
            if constexpr (BN) {
                w[0] = w[0] * sca.x + sha.x;
                w[1] = w[1] * sca.y + sha.y;
                w[2] = w[2] * sca.z + sha.z;
                w[3] = w[3] * sca.w + sha.w;
                w[4] = w[4] * scb.x + shb.x;
                w[5] = w[5] * scb.y + shb.y;
                w[6] = w[6] * scb.z + shb.z;
                w[7] = w[7] * scb.w + shb.w;
            }
            bf16x8 t;
#pragma unroll
            for (int j = 0; j < 8; ++j) t[j] = (__bf16)w[j];
            xa[nm] = t;
        }
        const unsigned short* wlp = Wfl + ((size_t)(kk * NF) * 64 + lane) * 8;
        const unsigned short* wrp = Wfr + ((size_t)(kk * NF) * 64 + lane) * 8;
#pragma unroll
        for (int nf = 0; nf < NF; ++nf) {
            bf16x8 wl = __builtin_bit_cast(bf16x8, *(const uint4*)(wlp + (size_t)nf * 64 * 8));
            bf16x8 wr = __builtin_bit_cast(bf16x8, *(const uint4*)(wrp + (size_t)nf * 64 * 8));
#pragma unroll
            for (int nm = 0; nm < 2; ++nm) {
                acc[nm][nf][0] = __builtin_amdgcn_mfma_f32_16x16x32_bf16(wl, xa[nm], acc[nm][nf][0], 0, 0, 0);
                acc[nm][nf][1] = __builtin_amdgcn_mfma_f32_16x16x32_bf16(wr, xa[nm], acc[nm][nf][1], 0, 0, 0);
            }
        }
    }

    // epilogue: +bias, pack 4 consecutive channels to bf16, store uint2
#pragma unroll
    for (int nf = 0; nf < NF; ++nf) {
        float4 blv = *(const float4*)(bl + nf * 16 + lg * 4);
        float4 brv = *(const float4*)(br + nf * 16 + lg * 4);
#pragma unroll
        for (int nm = 0; nm < 2; ++nm) {
            size_t base = (size_t)(nbase + nm * 16 + ll) * DO + nf * 16 + lg * 4;
            f32x4 a = acc[nm][nf][0];
            uint2 p;
            p.x = pk2(a[0] + blv.x, a[1] + blv.y);
            p.y = pk2(a[2] + blv.z, a[3] + blv.w);
            *(uint2*)(xl + base) = p;
            f32x4 r = acc[nm][nf][1];
            uint2 q;
            q.x = pk2(r[0] + brv.x, r[1] + brv.y);
            q.y = pk2(r[2] + brv.z, r[3] + brv.w);
            *(uint2*)(xr + base) = q;
        }
    }
}

// ------- per-node softmax attention + aggregate + bias + relu --------------
// R13 agg10 (proven best): 256-thread block = 16 nodes, 4 nodes per wave;
// four 16-lane subgroups keep 4 edges in flight with next-iteration prefetch.
// Stats + pool combine in LDS once per block (device-atomic amortization is
// worth the barrier — R12 lesson). Scalar inner loop (compiler-scheduled;
// inline-asm packed math regressed — R14 lesson). h output packed bf16.

template <int DO, bool WRITEH, int PBASE>
__global__ __launch_bounds__(256) void k_agg10(
        const unsigned short* __restrict__ xl, const unsigned short* __restrict__ xr,
        const int* __restrict__ off, const int* __restrict__ srcs,
        const float* __restrict__ att, const float* __restrict__ bias,
        const int* __restrict__ batch,
        unsigned short* __restrict__ hout, float* __restrict__ statbuf,
        float* __restrict__ rawpool) {
    constexpr int CPL = DO / 16;  // channels per lane
    using UT = typename std::conditional<CPL == 8, uint4,
               typename std::conditional<CPL == 4, uint2, unsigned>::type>::type;
    int wid = threadIdx.x >> 6;
    int lane = threadIdx.x & 63;
    int sg = lane >> 4;          // subgroup 0..3
    int sl = lane & 15;
    int cbase = sl * CPL;

    __shared__ float sO[16][DO];
    __shared__ int gb[16];
    if (threadIdx.x < 16) gb[threadIdx.x] = batch[blockIdx.x * 16 + threadIdx.x];

    float atv[CPL];
    if constexpr (CPL == 8) {
        float4 a0 = ((const float4*)att)[sl * 2], a1 = ((const float4*)att)[sl * 2 + 1];
        atv[0] = a0.x; atv[1] = a0.y; atv[2] = a0.z; atv[3] = a0.w;
        atv[4] = a1.x; atv[5] = a1.y; atv[6] = a1.z; atv[7] = a1.w;
    } else if constexpr (CPL == 4) {
        float4 a0 = ((const float4*)att)[sl];
        atv[0] = a0.x; atv[1] = a0.y; atv[2] = a0.z; atv[3] = a0.w;
    } else {
        float2 a0 = ((const float2*)att)[sl];
        atv[0] = a0.x; atv[1] = a0.y;
    }
    float bi[CPL];
#pragma unroll
    for (int i = 0; i < CPL; ++i) bi[i] = bias[cbase + i];

    int nb = blockIdx.x * 16 + wid * 4;
    for (int n = 0; n < 4; ++n) {
        int node = nb + n;
        float xrv[CPL];
        unpk(*(const UT*)(xr + (size_t)node * DO + cbase), xrv);
        float spart = 0.f;
        float acc[CPL] = {};
        int e0 = off[node], e1 = off[node + 1];

        int jp = e0 + sg;                 // prefetch iteration 0
        bool actp = (jp < e1);
        int srcp = srcs[actp ? jp : e1 - 1];
        UT up = *(const UT*)(xl + (size_t)srcp * DO + cbase);

        for (int jb = e0; jb < e1; jb += 4) {
            UT u = up;
            bool act = actp;
            if (jb + 4 < e1) {            // prefetch next iteration
                int jn = jb + 4 + sg;
                actp = (jn < e1);
                int srcn = srcs[actp ? jn : e1 - 1];
                up = *(const UT*)(xl + (size_t)srcn * DO + cbase);
            }
            float v[CPL];
            unpk(u, v);
            float pd = 0.f;
#pragma unroll
            for (int i = 0; i < CPL; ++i) {
                float t = v[i] + xrv[i];
                t = fmaxf(t, 0.2f * t);       // leaky_relu, slope 0.2
                pd = fmaf(t, atv[i], pd);
            }
#pragma unroll
            for (int d = 1; d < 16; d <<= 1) pd += __shfl_xor(pd, d);
            float w = act ? __expf(pd) : 0.f;
            spart += w;
#pragma unroll
            for (int i = 0; i < CPL; ++i) acc[i] = fmaf(w, v[i], acc[i]);
        }
        spart += __shfl_xor(spart, 16);
        spart += __shfl_xor(spart, 32);
#pragma unroll
        for (int i = 0; i < CPL; ++i) {
            acc[i] += __shfl_xor(acc[i], 16);
            acc[i] += __shfl_xor(acc[i], 32);
        }
        if (sg == 0) {
            float inv = 1.f / spart;
            float o[CPL];
#pragma unroll
            for (int i = 0; i < CPL; ++i) {
                o[i] = fmaxf(fmaf(acc[i], inv, bi[i]), 0.f);
                sO[wid * 4 + n][cbase + i] = o[i];
            }
            if constexpr (WRITEH) {
                if constexpr (CPL == 8) {
                    uint4 pkd;
                    pkd.x = pk2(o[0], o[1]); pkd.y = pk2(o[2], o[3]);
                    pkd.z = pk2(o[4], o[5]); pkd.w = pk2(o[6], o[7]);
                    *(uint4*)(hout + (size_t)node * DO + cbase) = pkd;
                } else if constexpr (CPL == 4) {
                    uint2 pkd;
                    pkd.x = pk2(o[0], o[1]); pkd.y = pk2(o[2], o[3]);
                    *(uint2*)(hout + (size_t)node * DO + cbase) = pkd;
                } else {
                    *(unsigned*)(hout + (size_t)node * DO + cbase) = pk2(o[0], o[1]);
                }
            }
        }
    }
    __syncthreads();
    int t = threadIdx.x;
    if (t < DO) {
        float pa = sO[0][t];
        float s = pa, q = pa * pa;
        int cg = gb[0];
#pragma unroll
        for (int w = 1; w < 16; ++w) {
            float vw = sO[w][t];
            s += vw;
            q += vw * vw;
            int g = gb[w];
            if (g != cg) {               // group boundary (sorted batch)
                atomicAdd(&rawpool[(size_t)cg * 224 + PBASE + t], pa);
                pa = 0.f;
                cg = g;
            }
            pa += vw;
        }
        atomicAdd(&rawpool[(size_t)cg * 224 + PBASE + t], pa);
        float* sb = statbuf + (size_t)(blockIdx.x & (NSLOT - 1)) * 2 * DO;
        atomicAdd(&sb[t], s);
        atomicAdd(&sb[DO + t], q);
    }
}

// ---------------- head: build pooled row (BN affines from fused stats), ----
// ---------------- lin1+relu; then BN5+lin2+sigmoid/log_softmax -------------

__global__ __launch_bounds__(128) void k_head1(
        const float* __restrict__ rawpool,
        const int* __restrict__ gstart, const int* __restrict__ gend,
        const float* __restrict__ st1, const float* __restrict__ st2,
        const float* __restrict__ st3,
        const float* __restrict__ g1, const float* __restrict__ b1,
        const float* __restrict__ g2, const float* __restrict__ b2,
        const float* __restrict__ g3, const float* __restrict__ b3,
        const float* __restrict__ W1, const float* __restrict__ b1l,
        float* __restrict__ z) {
    __shared__ float row[256];
    int g = blockIdx.x, c = threadIdx.x;  // 128 threads
    float cnt = (float)(gend[g] - gstart[g]);
    {
        float s = 0.f, q = 0.f;
        for (int k = 0; k < NSLOT; ++k) {
            s += st1[k * 256 + c];
            q += st1[k * 256 + 128 + c];
        }
        float mean = s * (1.f / NN);
        float var = q * (1.f / NN) - mean * mean;
        float sc = g1[c] * rsqrtf(var + BN_EPS);
        float sh = b1[c] - mean * sc;
        row[c] = sc * rawpool[(size_t)g * 224 + c] + sh * cnt;
    }
    {
        float sc, sh, rv;
        if (c < 64) {
            float s = 0.f, q = 0.f;
            for (int k = 0; k < NSLOT; ++k) {
                s += st2[k * 128 + c];
                q += st2[k * 128 + 64 + c];
            }
            float mean = s * (1.f / NN);
            float var = q * (1.f / NN) - mean * mean;
            sc = g2[c] * rsqrtf(var + BN_EPS);
            sh = b2[c] - mean * sc;
            rv = rawpool[(size_t)g * 224 + 128 + c];
        } else {
            int j = (c < 96) ? c - 64 : c - 96;
            float s = 0.f, q = 0.f;
            for (int k = 0; k < NSLOT; ++k) {
                s += st3[k * 64 + j];
                q += st3[k * 64 + 32 + j];
            }
            float mean = s * (1.f / NN);
            float var = q * (1.f / NN) - mean * mean;
            sc = g3[j] * rsqrtf(var + BN_EPS);
            sh = b3[j] - mean * sc;
            rv = rawpool[(size_t)g * 224 + 192 + j];
        }
        row[128 + c] = sc * rv + sh * cnt;
    }
    __syncthreads();
    float acc = b1l[c];
#pragma unroll 16
    for (int k = 0; k < 256; ++k) acc += row[k] * W1[k * 128 + c];
    z[g * 128 + c] = acc > 0.f ? acc : 0.f;
}

__global__ void k_head2(const float* __restrict__ z, const float* __restrict__ g5,
                        const float* __restrict__ b5, const float* __restrict__ W2,
                        const float* __restrict__ b2, float* __restrict__ out) {
    __shared__ float row[128];
    __shared__ float lg[3];
    int g = blockIdx.x, t = threadIdx.x;
    double s = 0.0, q = 0.0;
    for (int gg = 0; gg < NG; ++gg) {
        float v = z[gg * 128 + t];
        s += v;
        q += (double)v * v;
    }
    double mean = s * (1.0 / NG);
    double var = q * (1.0 / NG) - mean * mean;
    float sc = g5[t] * rsqrtf((float)var + BN_EPS);
    float sh = b5[t] - (float)mean * sc;
    row[t] = z[g * 128 + t] * sc + sh;
    __syncthreads();
    if (t < 3) {
        float acc = b2[t];
        for (int k = 0; k < 128; ++k) acc += row[k] * W2[k * 3 + t];
        lg[t] = acc;
    }
    __syncthreads();
    if (t == 0) {
        float l0 = lg[0], l1 = lg[1], l2 = lg[2];
        float mx = fmaxf(l0, fmaxf(l1, l2));
        float lse = mx + logf(expf(l0 - mx) + expf(l1 - mx) + expf(l2 - mx));
        out[g * 3 + 0] = 1.f / (1.f + expf(-l0));
        out[g * 3 + 1] = 1.f / (1.f + expf(-l1));
        out[g * 3 + 2] = 1.f / (1.f + expf(-l2));
        out[NG * 3 + g * 3 + 0] = l0 - lse;
        out[NG * 3 + g * 3 + 1] = l1 - lse;
        out[NG * 3 + g * 3 + 2] = l2 - lse;
    }
}

// ---------------------------------------------------------------------------

extern "C" void kernel_launch(void* const* d_in, const int* in_sizes, int n_in,
                              void* d_out, int out_size, void* d_ws, size_t ws_size,
                              hipStream_t stream) {
    const float* x   = (const float*)d_in[0];
    const int* ei    = (const int*)d_in[1];
    const int* batch = (const int*)d_in[2];
    auto F = [&](int i) { return (const float*)d_in[i]; };

    char* ws = (char*)d_ws;
    size_t o = 0;
    auto alloc = [&](size_t bytes) {
        char* p = ws + o;
        o += (bytes + 255) & ~(size_t)255;
        return p;
    };
    int* csr_off  = (int*)alloc((NN + 1) * 4);
    int* wofs     = (int*)alloc(NN * 4);
    int* bsum     = (int*)alloc(256 * 4);
    int* csr_src  = (int*)alloc((size_t)NT * 4);
    unsigned short* xl = (unsigned short*)alloc((size_t)NN * 128 * 2);
    unsigned short* xr = (unsigned short*)alloc((size_t)NN * 128 * 2);
    unsigned short* h1 = (unsigned short*)alloc((size_t)NN * 128 * 2);
    unsigned short* h2 = (unsigned short*)alloc((size_t)NN * 64 * 2);
    float* z      = (float*)alloc(NG * 128 * 4);
    // zero-init chunk: counts|stat1|stat2|stat3|rawpool|gstart|gend (one memset)
    size_t zbytes = (size_t)NN * 4 + (size_t)NSLOT * (256 + 128 + 64) * 4 +
                    (size_t)NG * 224 * 4 + 2 * NG * 4;
    char* zchunk  = alloc(zbytes);
    int* counts   = (int*)zchunk;                         // [NN]
    float* stat1  = (float*)(zchunk + (size_t)NN * 4);    // [64][256]
    float* stat2  = stat1 + NSLOT * 256;                  // [64][128]
    float* stat3  = stat2 + NSLOT * 128;                  // [64][64]
    float* rawpool = stat3 + NSLOT * 64;                  // [256][224]
    int* gstart   = (int*)(rawpool + (size_t)NG * 224);   // [256]
    int* gend     = gstart + NG;                          // [256]
    unsigned short* wfl1 = (unsigned short*)alloc(128 * 128 * 2);
    unsigned short* wfr1 = (unsigned short*)alloc(128 * 128 * 2);
    unsigned short* wfl2 = (unsigned short*)alloc(128 * 64 * 2);
    unsigned short* wfr2 = (unsigned short*)alloc(128 * 64 * 2);
    unsigned short* wfl3 = (unsigned short*)alloc(64 * 32 * 2);
    unsigned short* wfr3 = (unsigned short*)alloc(64 * 32 * 2);

    hipMemsetAsync(zchunk, 0, zbytes, stream);

    // hist || W swizzle (independent work, one dispatch)
    k_pre<<<2048 + 26, 256, 0, stream>>>(ei, counts,
                                         F(3), F(5), F(11), F(13), F(19), F(21),
                                         wfl1, wfr1, wfl2, wfr2, wfl3, wfr3);
    k_scanA<<<NN / 256, 256, 0, stream>>>(counts, bsum);
    k_scanBC<<<NN / 256, 256, 0, stream>>>(counts, bsum, csr_off, wofs);
    k_scatter<<<NT / 1024, 256, 0, stream>>>(ei, batch, wofs, csr_src,
                                             gstart, gend);

    // ---- GAT layer 1: 128 -> 128 (stats + pool fused into agg) ----
    k_gemm2m<128, 128, false, float><<<NN / 128, 256, 0, stream>>>(
        x, wfl1, wfr1, F(4), F(6), nullptr, nullptr, nullptr, xl, xr);
    k_agg10<128, true, 0><<<NN / 16, 256, 0, stream>>>(
        xl, xr, csr_off, csr_src, F(7), F(8), batch, h1, stat1, rawpool);

    // ---- GAT layer 2: 128 -> 64 (bf16 h1; BN1 affine in prologue) ----
    k_gemm2m<128, 64, true, unsigned short><<<NN / 128, 256, 0, stream>>>(
        h1, wfl2, wfr2, F(12), F(14), stat1, F(9), F(10), xl, xr);
    k_agg10<64, true, 128><<<NN / 16, 256, 0, stream>>>(
        xl, xr, csr_off, csr_src, F(15), F(16), batch, h2, stat2, rawpool);

    // ---- GAT layer 3: 64 -> 32 (bf16 h2; h3 never materialized) ----
    k_gemm2m<64, 32, true, unsigned short><<<NN / 128, 256, 0, stream>>>(
        h2, wfl3, wfr3, F(20), F(22), stat2, F(17), F(18), xl, xr);
    k_agg10<32, false, 192><<<NN / 16, 256, 0, stream>>>(
        xl, xr, csr_off, csr_src, F(23), F(24), batch, nullptr, stat3, rawpool);

    // ---- head ----
    k_head1<<<NG, 128, 0, stream>>>(rawpool, gstart, gend, stat1, stat2, stat3,
                                    F(9), F(10), F(17), F(18), F(25), F(26),
                                    F(27), F(28), z);
    k_head2<<<NG, 128, 0, stream>>>(z, F(29), F(30), F(31), F(32), (float*)d_out);
}